// Round 5
// baseline (283.745 us; speedup 1.0000x reference)
//
#include <hip/hip_runtime.h>

// Problem constants (match reference)
#define BATCH 8192
#define TSTEPS 200
#define FEAT 16
#define HID 32
#define GATES 128   // 4*HID, Keras order: i | f | cc | o
#define DOUT 60
#define ROWS 16     // batch rows per block (one MFMA M-tile)
#define HSTRIDE 40  // LDS h row stride in halves (80 B)
#define LOG2E 1.44269504088896340736f

typedef __fp16 half2v __attribute__((ext_vector_type(2)));
typedef __fp16 half8v __attribute__((ext_vector_type(8)));
typedef float  float4v __attribute__((ext_vector_type(4)));

__device__ __forceinline__ half2v pkrtz(float a, float b) {
    return __builtin_amdgcn_cvt_pkrtz(a, b);
}

// sigmoid(x) where weights/bias are PRE-SCALED by log2(e):
// sigma = 1 / (1 + exp2(-xs))
__device__ __forceinline__ float sigm2(float xs) {
    float e = __builtin_amdgcn_exp2f(-xs);
    return __builtin_amdgcn_rcpf(1.0f + e);
}

// Single-wave persistent MFMA LSTM (NO barriers -> no vmcnt drain in chain).
// Block = 1 wave = 64 threads, owns 16 batch rows and ALL 128 gate columns
// (8 tiles: gate {i,f,cc,o} x unit-half {0,1}).
// Per step:
//   - issue x load for t+2 (stays in flight across steps; no barrier to drain it)
//   - acc = bias; acc += x_t*W (K=16 zero-padded to 32; garbage*0 = 0)
//   - ds_read_b128 h_t (same-wave lgkmcnt only), acc += h*U
//   - lane-local epilogue: lane owns (rows g*4+r, units {n16, n16+16}) for all
//     4 gates -> c update fully in VGPRs; h written as ONE b32/row (units
//     interleaved: pos = 2*(u&15) + (u>>4)), exactly 2 lanes/bank = free.
//   - U fragment is pre-permuted in k to match the interleaved h storage.
// Fragment layouts (gfx950, verified m89/m91/m120):
//   A[m][k]: m = lane&15, k = (lane>>4)*8 + j
//   B[k][n]: n = lane&15, k = (lane>>4)*8 + j
//   D[m][n]: n = lane&15, m = (lane>>4)*4 + r
__global__ __launch_bounds__(64, 1) void lstm_mfma(
    const float* __restrict__ x,    // [B, T, F]
    const float* __restrict__ W,    // [F, 128]
    const float* __restrict__ U,    // [H, 128]
    const float* __restrict__ bg,   // [128]
    const float* __restrict__ W1,   // [H, 60]
    const float* __restrict__ b1,   // [60]
    const float* __restrict__ W2,   // [H, 60]
    const float* __restrict__ b2,   // [60]
    float* __restrict__ out)        // [2 * B * 60] (long || lat)
{
    const int lane = threadIdx.x;   // 0..63
    const int n16  = lane & 15;
    const int g    = lane >> 4;     // k-quad / row-quad
    const int b0   = blockIdx.x * ROWS;

    __shared__ __align__(16) __fp16 hbuf[2][ROWS * HSTRIDE];

    // ---- stationary B-frags: U (k-permuted, K=32) and W (K=16 zero-padded) ----
    // Gates i(0), f(1), o(3) pre-scaled by log2(e) so sigmoid skips the mul.
    half8v bU[4][2], bW[4][2];
    float  bias[4][2];
    #pragma unroll
    for (int gate = 0; gate < 4; gate++) {
        const float sc = (gate == 2) ? 1.0f : LOG2E;
        #pragma unroll
        for (int uh = 0; uh < 2; uh++) {
            const int col = gate * 32 + uh * 16 + n16;
            half8v u8, w8;
            #pragma unroll
            for (int j = 0; j < 8; j++) {
                const int s = g * 8 + j;                  // k-slot
                const int u = (s >> 1) | ((s & 1) << 4);  // interleaved unit
                u8[j] = (__fp16)(U[u * GATES + col] * sc);
                w8[j] = (s < FEAT) ? (__fp16)(W[s * GATES + col] * sc) : (__fp16)0.f;
            }
            bU[gate][uh] = u8;
            bW[gate][uh] = w8;
            bias[gate][uh] = bg[col] * sc;
        }
    }

    // zero h_0 buffer (same wave -> ordering via lgkmcnt, no barrier)
    #pragma unroll
    for (int i = lane; i < ROWS * HSTRIDE; i += 64) hbuf[0][i] = (__fp16)0.f;

    float cst[2][4] = {{0.f,0.f,0.f,0.f},{0.f,0.f,0.f,0.f}};

    // x source: lane reads feats (g&1)*8 .. +7 of row n16 (quads 2,3 duplicate
    // quads 0,1 — their products hit zero W weights, so values don't matter)
    const float* xrow = x + (size_t)(b0 + n16) * TSTEPS * FEAT + (g & 1) * 8;

    // depth-2 prefetch pipeline
    float4 xa0 = *reinterpret_cast<const float4*>(xrow);
    float4 xb0 = *reinterpret_cast<const float4*>(xrow + 4);
    float4 xa1 = *reinterpret_cast<const float4*>(xrow + FEAT);
    float4 xb1 = *reinterpret_cast<const float4*>(xrow + FEAT + 4);

    #pragma unroll 2
    for (int t = 0; t < TSTEPS; t++) {
        // issue x_{t+2} loads NOW — two full steps of slack, no barrier drain
        float4 xa2 = make_float4(0.f,0.f,0.f,0.f), xb2 = xa2;
        if (t + 2 < TSTEPS) {
            xa2 = *reinterpret_cast<const float4*>(xrow + (size_t)(t + 2) * FEAT);
            xb2 = *reinterpret_cast<const float4*>(xrow + (size_t)(t + 2) * FEAT + 4);
        }

        // start h_t read early (latency overlaps x MFMAs)
        half8v ha = *reinterpret_cast<const half8v*>(
            &hbuf[t & 1][n16 * HSTRIDE + g * 8]);

        // pack x_t A-frag
        union { half8v v; half2v h2[4]; } ax;
        ax.h2[0] = pkrtz(xa0.x, xa0.y);
        ax.h2[1] = pkrtz(xa0.z, xa0.w);
        ax.h2[2] = pkrtz(xb0.x, xb0.y);
        ax.h2[3] = pkrtz(xb0.z, xb0.w);

        float4v acc[4][2];
        #pragma unroll
        for (int gate = 0; gate < 4; gate++)
            #pragma unroll
            for (int uh = 0; uh < 2; uh++) {
                float4v a = {bias[gate][uh], bias[gate][uh],
                             bias[gate][uh], bias[gate][uh]};
                acc[gate][uh] =
                    __builtin_amdgcn_mfma_f32_16x16x32_f16(ax.v, bW[gate][uh], a, 0, 0, 0);
            }

        #pragma unroll
        for (int gate = 0; gate < 4; gate++)
            #pragma unroll
            for (int uh = 0; uh < 2; uh++)
                acc[gate][uh] =
                    __builtin_amdgcn_mfma_f32_16x16x32_f16(ha, bU[gate][uh], acc[gate][uh], 0, 0, 0);

        // ---- lane-local epilogue: rows g*4+r, units n16 (uh=0), n16+16 (uh=1) ----
        __fp16* hw = &hbuf[(t + 1) & 1][0];
        #pragma unroll
        for (int r = 0; r < 4; r++) {
            float hh[2];
            #pragma unroll
            for (int uh = 0; uh < 2; uh++) {
                float iv = sigm2(acc[0][uh][r]);
                float fv = sigm2(acc[1][uh][r]);
                float cc = acc[2][uh][r];
                float ov = sigm2(acc[3][uh][r]);
                float cn = fmaf(fv, cst[uh][r], iv * fmaxf(cc, 0.f));
                cst[uh][r] = cn;
                hh[uh] = ov * fmaxf(cn, 0.f);
            }
            // one b32 per row: positions 2*n16 (unit n16), 2*n16+1 (unit n16+16)
            *reinterpret_cast<half2v*>(&hw[(g * 4 + r) * HSTRIDE + n16 * 2]) =
                pkrtz(hh[0], hh[1]);
        }

        xa0 = xa1; xb0 = xb1; xa1 = xa2; xb1 = xb2;
    }

    // ---- heads: h_T is in hbuf[TSTEPS&1] with interleaved unit positions ----
    const __fp16* hf = &hbuf[TSTEPS & 1][0];
    for (int idx = lane; idx < ROWS * DOUT; idx += 64) {
        const int row = idx / DOUT;
        const int d   = idx - row * DOUT;
        float s1 = b1[d], s2 = b2[d];
        #pragma unroll
        for (int u = 0; u < HID; u++) {
            const int p = ((u & 15) << 1) | (u >> 4);   // interleaved position
            float hv = (float)hf[row * HSTRIDE + p];
            s1 = fmaf(hv, W1[u * DOUT + d], s1);
            s2 = fmaf(hv, W2[u * DOUT + d], s2);
        }
        out[(size_t)(b0 + row) * DOUT + d] = s1;
        out[(size_t)BATCH * DOUT + (size_t)(b0 + row) * DOUT + d] = s2;
    }
}

extern "C" void kernel_launch(void* const* d_in, const int* in_sizes, int n_in,
                              void* d_out, int out_size, void* d_ws, size_t ws_size,
                              hipStream_t stream) {
    const float* x  = (const float*)d_in[0];
    const float* W  = (const float*)d_in[1];
    const float* U  = (const float*)d_in[2];
    const float* bg = (const float*)d_in[3];
    const float* W1 = (const float*)d_in[4];
    const float* b1 = (const float*)d_in[5];
    const float* W2 = (const float*)d_in[6];
    const float* b2 = (const float*)d_in[7];
    float* out = (float*)d_out;

    dim3 grid(BATCH / ROWS);   // 512 single-wave blocks (2 waves/CU)
    dim3 block(64);
    lstm_mfma<<<grid, block, 0, stream>>>(x, W, U, bg, W1, b1, W2, b2, out);
}

// Round 6
// 282.572 us; speedup vs baseline: 1.0042x; 1.0042x over previous
//
#include <hip/hip_runtime.h>

// Problem constants (match reference)
#define BATCH 8192
#define TSTEPS 200
#define FEAT 16
#define HID 32
#define GATES 128   // 4*HID, Keras order: i | f | cc | o
#define DOUT 60
#define ROWS 16     // batch rows per block (one MFMA M-tile)
#define HSTRIDE 40  // LDS h row stride in halves (80 B)
#define LOG2E 1.44269504088896340736f

typedef __fp16 half2v __attribute__((ext_vector_type(2)));
typedef __fp16 half8v __attribute__((ext_vector_type(8)));
typedef float  float4v __attribute__((ext_vector_type(4)));

__device__ __forceinline__ half2v pkrtz(float a, float b) {
    return __builtin_amdgcn_cvt_pkrtz(a, b);
}

// sigmoid(x) with weights/bias PRE-SCALED by log2(e): 1 / (1 + exp2(-xs))
__device__ __forceinline__ float sigm2(float xs) {
    float e = __builtin_amdgcn_exp2f(-xs);
    return __builtin_amdgcn_rcpf(1.0f + e);
}

// Workgroup barrier WITHOUT the vmcnt(0) drain __syncthreads() forces.
// LDS cross-wave visibility needs only lgkmcnt(0); global loads (our x
// prefetch) stay in flight across the barrier. Memory clobber stops the
// compiler from caching LDS values across it.
__device__ __forceinline__ void lgkm_barrier() {
    asm volatile("s_waitcnt lgkmcnt(0)\n\ts_barrier" ::: "memory");
}

// 2-wave MFMA LSTM, unit-split, loads never drained.
// Block = 128 threads = 2 waves, owns 16 batch rows.
// Wave uh owns h-units [16uh, 16uh+16): 4 gate tiles (cols gate*32+16uh+n16).
// Per step (one lgkm-only barrier):
//   barrier (h_t visible) -> ds_read_b128 h_t A-frag -> prefetch x_{t+2}
//   -> 4 W-MFMAs (acc=bias, K=16 zero-padded, fills ha latency)
//   -> 4 U-MFMAs -> lane-local epilogue (i,f,cc,o same lane) -> b16 h-writes.
// Fragment layouts (gfx950, verified m89/m91/m120):
//   A[m][k]: m = lane&15, k = (lane>>4)*8 + j
//   B[k][n]: n = lane&15, k = (lane>>4)*8 + j
//   D[m][n]: n = lane&15, m = (lane>>4)*4 + r
__global__ __launch_bounds__(128, 1) void lstm_mfma(
    const float* __restrict__ x,    // [B, T, F]
    const float* __restrict__ W,    // [F, 128]
    const float* __restrict__ U,    // [H, 128]
    const float* __restrict__ bg,   // [128]
    const float* __restrict__ W1,   // [H, 60]
    const float* __restrict__ b1,   // [60]
    const float* __restrict__ W2,   // [H, 60]
    const float* __restrict__ b2,   // [60]
    float* __restrict__ out)        // [2 * B * 60] (long || lat)
{
    const int tid  = threadIdx.x;
    const int lane = tid & 63;
    const int uh   = tid >> 6;      // unit-half: 0 or 1
    const int n16  = lane & 15;
    const int g    = lane >> 4;     // k-quad (A/B) / row-quad (D)
    const int b0   = blockIdx.x * ROWS;

    __shared__ __align__(16) __fp16 hbuf[2][ROWS * HSTRIDE];

    // ---- stationary B-frags: U (K=32) and W (K=16 zero-padded) ----
    // Gates i(0), f(1), o(3) pre-scaled by log2(e); cc(2) unscaled.
    half8v bU[4], bW[4];
    float  bias[4];
    #pragma unroll
    for (int gate = 0; gate < 4; gate++) {
        const float sc = (gate == 2) ? 1.0f : LOG2E;
        const int col = gate * 32 + uh * 16 + n16;
        half8v u8, w8;
        #pragma unroll
        for (int j = 0; j < 8; j++) {
            const int k = g * 8 + j;
            u8[j] = (__fp16)(U[k * GATES + col] * sc);
            w8[j] = (k < FEAT) ? (__fp16)(W[k * GATES + col] * sc) : (__fp16)0.f;
        }
        bU[gate] = u8;
        bW[gate] = w8;
        bias[gate] = bg[col] * sc;
    }

    // zero h_0 (visible to both waves via the t=0 loop-top barrier)
    for (int i = tid; i < ROWS * HSTRIDE; i += 128) hbuf[0][i] = (__fp16)0.f;

    float cst[4] = {0.f, 0.f, 0.f, 0.f};   // cell state: rows g*4+r, unit 16uh+n16

    // x source: lane reads feats (g&1)*8..+7 of row n16 (quads 2,3 duplicate
    // quads 0,1 — those products hit zero-padded W weights)
    const float* xrow = x + (size_t)(b0 + n16) * TSTEPS * FEAT + (g & 1) * 8;

    // depth-2 prefetch: loads stay in flight across the lgkm-only barrier
    float4 xa0 = *reinterpret_cast<const float4*>(xrow);
    float4 xb0 = *reinterpret_cast<const float4*>(xrow + 4);
    float4 xa1 = *reinterpret_cast<const float4*>(xrow + FEAT);
    float4 xb1 = *reinterpret_cast<const float4*>(xrow + FEAT + 4);

    #pragma unroll 2
    for (int t = 0; t < TSTEPS; t++) {
        lgkm_barrier();   // h_t (written at end of step t-1) visible; x loads untouched

        // h_t A-frag: row n16, units g*8..g*8+7 (b128, 2-way banks = free)
        half8v ha = *reinterpret_cast<const half8v*>(
            &hbuf[t & 1][n16 * HSTRIDE + g * 8]);

        // issue x_{t+2}
        float4 xa2 = make_float4(0.f, 0.f, 0.f, 0.f), xb2 = xa2;
        if (t + 2 < TSTEPS) {
            xa2 = *reinterpret_cast<const float4*>(xrow + (size_t)(t + 2) * FEAT);
            xb2 = *reinterpret_cast<const float4*>(xrow + (size_t)(t + 2) * FEAT + 4);
        }

        // pack x_t A-frag
        union { half8v v; half2v h2[4]; } ax;
        ax.h2[0] = pkrtz(xa0.x, xa0.y);
        ax.h2[1] = pkrtz(xa0.z, xa0.w);
        ax.h2[2] = pkrtz(xb0.x, xb0.y);
        ax.h2[3] = pkrtz(xb0.z, xb0.w);

        // acc = bias; acc += x_t*W  (independent of ha -> fills its latency)
        float4v acc[4];
        #pragma unroll
        for (int gate = 0; gate < 4; gate++) {
            float4v a = {bias[gate], bias[gate], bias[gate], bias[gate]};
            acc[gate] = __builtin_amdgcn_mfma_f32_16x16x32_f16(ax.v, bW[gate], a, 0, 0, 0);
        }

        #pragma unroll
        for (int gate = 0; gate < 4; gate++)
            acc[gate] = __builtin_amdgcn_mfma_f32_16x16x32_f16(ha, bU[gate], acc[gate], 0, 0, 0);

        // ---- lane-local epilogue: rows g*4+r, unit 16uh+n16 ----
        __fp16* hw = &hbuf[(t + 1) & 1][0];
        #pragma unroll
        for (int r = 0; r < 4; r++) {
            float iv = sigm2(acc[0][r]);
            float fv = sigm2(acc[1][r]);
            float cc = acc[2][r];
            float ov = sigm2(acc[3][r]);
            float cn = fmaf(fv, cst[r], iv * fmaxf(cc, 0.f));
            cst[r] = cn;
            float hn = ov * fmaxf(cn, 0.f);
            hw[(g * 4 + r) * HSTRIDE + uh * 16 + n16] = (__fp16)hn;
        }

        xa0 = xa1; xb0 = xb1; xa1 = xa2; xb1 = xb2;
    }

    lgkm_barrier();   // h_T complete in hbuf[TSTEPS&1]

    // ---- heads: out = h_T @ W1/W2 + b (fp32 math, h from LDS) ----
    const __fp16* hf = &hbuf[TSTEPS & 1][0];
    for (int idx = tid; idx < ROWS * DOUT; idx += 128) {
        const int row = idx / DOUT;
        const int d   = idx - row * DOUT;
        float s1 = b1[d], s2 = b2[d];
        #pragma unroll
        for (int u = 0; u < HID; u++) {
            float hv = (float)hf[row * HSTRIDE + u];
            s1 = fmaf(hv, W1[u * DOUT + d], s1);
            s2 = fmaf(hv, W2[u * DOUT + d], s2);
        }
        out[(size_t)(b0 + row) * DOUT + d] = s1;
        out[(size_t)BATCH * DOUT + (size_t)(b0 + row) * DOUT + d] = s2;
    }
}

extern "C" void kernel_launch(void* const* d_in, const int* in_sizes, int n_in,
                              void* d_out, int out_size, void* d_ws, size_t ws_size,
                              hipStream_t stream) {
    const float* x  = (const float*)d_in[0];
    const float* W  = (const float*)d_in[1];
    const float* U  = (const float*)d_in[2];
    const float* bg = (const float*)d_in[3];
    const float* W1 = (const float*)d_in[4];
    const float* b1 = (const float*)d_in[5];
    const float* W2 = (const float*)d_in[6];
    const float* b2 = (const float*)d_in[7];
    float* out = (float*)d_out;

    dim3 grid(BATCH / ROWS);   // 512 blocks x 2 waves = 1024 waves -> every SIMD busy
    dim3 block(128);
    lstm_mfma<<<grid, block, 0, stream>>>(x, W, U, bg, W1, b1, W2, b2, out);
}